// Round 14
// baseline (2889.643 us; speedup 1.0000x reference)
//
#include <hip/hip_runtime.h>
#include <cstdint>
#include <cstddef>

#define BATCH   8
#define NPTS    8192
#define NPOINT  2048
#define NSAMPLE 64
#define K0      67      // 3 + 64 input channels
#define C2      128

// Exact-order squared distance, matching XLA/numpy: ((dx*dx + dy*dy) + dz*dz),
// separate mul/add (no FMA contraction), round-to-nearest f32.
__device__ __forceinline__ float d2e(float ax, float ay, float az,
                                     float bx, float by, float bz) {
#pragma clang fp contract(off)
  float dx = ax - bx;
  float dy = ay - by;
  float dz = az - bz;
  float t0 = dx * dx;
  float t1 = dy * dy;
  float t2 = dz * dz;
  return (t0 + t1) + t2;
}

// ---- wave64 reductions via DPP; result broadcast via readlane (uniform).
__device__ __forceinline__ float dpp_max_f32(float x) {
  int v;
  v = __builtin_amdgcn_update_dpp(__float_as_int(x), __float_as_int(x), 0xB1, 0xF, 0xF, false);
  x = fmaxf(x, __int_as_float(v));
  v = __builtin_amdgcn_update_dpp(__float_as_int(x), __float_as_int(x), 0x4E, 0xF, 0xF, false);
  x = fmaxf(x, __int_as_float(v));
  v = __builtin_amdgcn_update_dpp(__float_as_int(x), __float_as_int(x), 0x141, 0xF, 0xF, false);
  x = fmaxf(x, __int_as_float(v));
  v = __builtin_amdgcn_update_dpp(__float_as_int(x), __float_as_int(x), 0x140, 0xF, 0xF, false);
  x = fmaxf(x, __int_as_float(v));
  v = __builtin_amdgcn_update_dpp(__float_as_int(x), __float_as_int(x), 0x142, 0xA, 0xF, false);
  x = fmaxf(x, __int_as_float(v));
  v = __builtin_amdgcn_update_dpp(__float_as_int(x), __float_as_int(x), 0x143, 0xC, 0xF, false);
  x = fmaxf(x, __int_as_float(v));
  return __int_as_float(__builtin_amdgcn_readlane(__float_as_int(x), 63));
}

__device__ __forceinline__ int dpp_min_i32(int x) {
  int v;
  v = __builtin_amdgcn_update_dpp(x, x, 0xB1, 0xF, 0xF, false); x = min(x, v);
  v = __builtin_amdgcn_update_dpp(x, x, 0x4E, 0xF, 0xF, false); x = min(x, v);
  v = __builtin_amdgcn_update_dpp(x, x, 0x141, 0xF, 0xF, false); x = min(x, v);
  v = __builtin_amdgcn_update_dpp(x, x, 0x140, 0xF, 0xF, false); x = min(x, v);
  v = __builtin_amdgcn_update_dpp(x, x, 0x142, 0xA, 0xF, false); x = min(x, v);
  v = __builtin_amdgcn_update_dpp(x, x, 0x143, 0xC, 0xF, false); x = min(x, v);
  return __builtin_amdgcn_readlane(x, 63);
}

__device__ __forceinline__ void st_rel(int* p, int v) {
  __hip_atomic_store(p, v, __ATOMIC_RELEASE, __HIP_MEMORY_SCOPE_AGENT);
}
__device__ __forceinline__ int ld_acq(int* p) {
  return __hip_atomic_load(p, __ATOMIC_ACQUIRE, __HIP_MEMORY_SCOPE_AGENT);
}

// Counter layout (PADDED: one counter per 256B line to kill false sharing +
// reader-storm on a single L2 line — R12/R13's producer slowdown):
//   prog[b]  -> ctr[b * 64]        (b = 0..7)
//   zcnt[B]  -> ctr[512 + B * 64]  (B = 0..7)
#define PROG(b) (ctr + (b) * 64)
#define ZCNT(B) (ctr + 512 + (B) * 64)

// =============================================================================
// Mega kernel: blocks 0-7 = FPS producers (R9 body + padded-line publish every
// 32 iters). Blocks 8.. = workers: zfeat tiles (FPS-independent), then
// per-wave {spin on progress, inline ball-query, MLP + max-pool}. Monotone
// frontier => deadlock-free; spins carry poll guards (wrong answer, not hang).
// =============================================================================
__global__ __launch_bounds__(512, 1) void mega_kernel(
    const float* __restrict__ xyz, const float* __restrict__ feat,
    const float* __restrict__ W0, const float* __restrict__ W1,
    const float* __restrict__ W2, const float* __restrict__ wsp,
    float* __restrict__ szp, int* __restrict__ ctr,
    float* __restrict__ out_xyz, float* __restrict__ out_feat,
    float* __restrict__ out_inds) {
  const int tid = threadIdx.x;
  const int lane = tid & 63;

  if (blockIdx.x < 8) {
    // ======================= FPS producer (R9 body) ========================
    const int b = blockIdx.x;
    const int w = tid >> 6;
    __shared__ float2 sxy[NPTS];
    __shared__ float  szl[NPTS];
    __shared__ unsigned long long wred[2][8] __attribute__((aligned(16)));

    const float* xb = xyz + (size_t)b * NPTS * 3;
    for (int k = 0; k < 16; k++) {
      int i = tid + k * 512;
      sxy[i] = make_float2(xb[i * 3 + 0], xb[i * 3 + 1]);
      szl[i] = xb[i * 3 + 2];
    }
    __syncthreads();

    const float2 q0xy = sxy[0];
    const float q0x = q0xy.x, q0y = q0xy.y, q0z = szl[0];

    const int base = tid * 16;
    float px[16], py[16], pz[16], dd[16];
#pragma unroll
    for (int j = 0; j < 16; j++) {
      float2 xy = sxy[base + j];
      px[j] = xy.x; py[j] = xy.y; pz[j] = szl[base + j];
      dd[j] = d2e(px[j], py[j], pz[j], q0x, q0y, q0z);
    }
    if (tid == 0) {
      out_inds[b * NPOINT] = 0.f;
      out_xyz[(size_t)b * NPOINT * 3 + 0] = q0x;
      out_xyz[(size_t)b * NPOINT * 3 + 1] = q0y;
      out_xyz[(size_t)b * NPOINT * 3 + 2] = q0z;
    }
    {
      float bv = dd[0]; int bj = base;
#pragma unroll
      for (int j = 1; j < 16; j++) {
        bool better = dd[j] > bv;
        bv = better ? dd[j] : bv;
        bj = better ? base + j : bj;
      }
      float vm = dpp_max_f32(bv);
      int ci = (bv == vm) ? bj : 0x7FFFFFFF;
      int widx = dpp_min_i32(ci);
      if (lane == 0)
        wred[0][w] = ((unsigned long long)(~__float_as_uint(vm)) << 32) | (unsigned)widx;
    }
    __syncthreads();

    for (int t = 1; t < NPOINT; ++t) {
      const ulonglong2* wv = (const ulonglong2*)wred[(t - 1) & 1];
      ulonglong2 p0 = wv[0], p1 = wv[1], p2 = wv[2], p3 = wv[3];
      unsigned long long g0 = (p0.y < p0.x) ? p0.y : p0.x;
      unsigned long long g1 = (p1.y < p1.x) ? p1.y : p1.x;
      unsigned long long g2 = (p2.y < p2.x) ? p2.y : p2.x;
      unsigned long long g3 = (p3.y < p3.x) ? p3.y : p3.x;
      g0 = (g1 < g0) ? g1 : g0; g2 = (g3 < g2) ? g3 : g2;
      g0 = (g2 < g0) ? g2 : g0;
      const int nxt = (int)(g0 & 0xFFFFFFFFu);
      const float2 qxy = sxy[nxt];
      const float qx = qxy.x, qy = qxy.y, qz = szl[nxt];
      if (tid == 0) {
        out_inds[b * NPOINT + t] = (float)nxt;
        out_xyz[((size_t)b * NPOINT + t) * 3 + 0] = qx;
        out_xyz[((size_t)b * NPOINT + t) * 3 + 1] = qy;
        out_xyz[((size_t)b * NPOINT + t) * 3 + 2] = qz;
        if ((t & 31) == 31) st_rel(PROG(b), t + 1);   // padded line, release
      }

      float d0 = d2e(px[0], py[0], pz[0], qx, qy, qz);
      dd[0] = fminf(dd[0], d0);
      float bv = dd[0]; int bj = base;
#pragma unroll
      for (int j = 1; j < 16; j++) {
        float d = d2e(px[j], py[j], pz[j], qx, qy, qz);
        dd[j] = fminf(dd[j], d);
        bool better = dd[j] > bv;
        bv = better ? dd[j] : bv;
        bj = better ? base + j : bj;
      }
      float vm = dpp_max_f32(bv);
      int ci = (bv == vm) ? bj : 0x7FFFFFFF;
      int widx = dpp_min_i32(ci);
      if (lane == 0)
        wred[t & 1][w] = ((unsigned long long)(~__float_as_uint(vm)) << 32) | (unsigned)widx;
      __syncthreads();
    }
    if (tid == 0) st_rel(PROG(b), NPOINT);
    return;
  }

  // =========================== worker block ================================
  const int wb = blockIdx.x - 8;       // 0..511
  const int w8 = tid >> 6;             // wave 0..7
  __shared__ float ftile[64][64];
  __shared__ float sxyzt[192];
  __shared__ float ylds2[8][2][64];
  __shared__ int   blds8[8][64];

  // ---- phase A: two zfeat tiles (independent of FPS)
  for (int tt = 0; tt < 2; tt++) {
    const int bt = wb * 2 + tt;
    const int B = bt >> 7, nt = bt & 127;
    const float* fb = feat + (size_t)B * 64 * NPTS + (size_t)nt * 64;
    for (int r = w8; r < 64; r += 8)
      ftile[r][lane] = fb[(size_t)r * NPTS + lane];
    if (tid < 192)
      sxyzt[tid] = xyz[((size_t)B * NPTS + (size_t)nt * 64) * 3 + tid];
    float w0x = W0[lane * K0 + 0], w0y = W0[lane * K0 + 1], w0z = W0[lane * K0 + 2];
    float wf[64];
#pragma unroll
    for (int i = 0; i < 64; i++) wf[i] = W0[lane * K0 + 3 + i];
    const float s0 = wsp[640 + lane];
    __syncthreads();
    float* ob = szp + ((size_t)B * NPTS + (size_t)nt * 64) * 64;
    for (int u = w8; u < 64; u += 8) {
      float acc = w0x * sxyzt[u * 3 + 0] + w0y * sxyzt[u * 3 + 1] + w0z * sxyzt[u * 3 + 2];
#pragma unroll
      for (int i = 0; i < 64; i++) acc = fmaf(wf[i], ftile[i][u], acc);
      ob[(size_t)u * 64 + lane] = acc * s0;
    }
    __syncthreads();
    if (tid == 0) {
      __threadfence();                               // all block stores -> L2 wb
      __hip_atomic_fetch_add(ZCNT(B), 1, __ATOMIC_RELEASE, __HIP_MEMORY_SCOPE_AGENT);
    }
  }

  // ---- phase B: wait until this batch's szp is fully built
  const int B0 = wb >> 6;              // 64 worker blocks per batch
  {
    int guard = 0;
    while (ld_acq(ZCNT(B0)) < 128 && ++guard < (1 << 18))
      __builtin_amdgcn_s_sleep(32);
  }
  __syncthreads();

  // ---- phase C: per-wave {spin, ball-query, MLP}
  float4 w1v[16], w2av[16], w2bv[16];
  const float4* W1r = (const float4*)(W1 + lane * 64);
  const float4* W2ar = (const float4*)(W2 + lane * 64);
  const float4* W2br = (const float4*)(W2 + (lane + 64) * 64);
#pragma unroll
  for (int i = 0; i < 16; i++) { w1v[i] = W1r[i]; w2av[i] = W2ar[i]; w2bv[i] = W2br[i]; }
  const float4 Aq = ((const float4*)wsp)[lane];
  const float sc1l = wsp[256 + lane], sh1l = wsp[320 + lane];
  const float sc2al = wsp[384 + lane], sh2al = wsp[512 + lane];
  const float sc2bl = wsp[448 + lane], sh2bl = wsp[576 + lane];
  const float RR = (float)(0.4 * 0.4);

  float* yA = ylds2[w8][0];
  float* yB = ylds2[w8][1];
  const float4* yva = (const float4*)yA;
  const float4* yvb = (const float4*)yB;
  int* bl = blds8[w8];
  const float* xb = xyz + (size_t)B0 * NPTS * 3;
  const float* szb = szp + (size_t)B0 * NPTS * 64;

  for (int qi = 0; qi < 4; qi++) {
    const int q = wb * 32 + qi * 8 + w8;
    const int p = q & 2047;

    {
      int guard = 0;
      while (ld_acq(PROG(B0)) < p + 1 && ++guard < (1 << 18))
        __builtin_amdgcn_s_sleep(32);
    }
    const float cx = out_xyz[(size_t)q * 3 + 0];
    const float cy = out_xyz[(size_t)q * 3 + 1];
    const float cz = out_xyz[(size_t)q * 3 + 2];
    const float hc = Aq.w - (Aq.x * cx + Aq.y * cy + Aq.z * cz);

    // --- inline ball query (exact logic of validated ballq kernel)
    int cnt = 0, firsti = -1;
    for (int base2 = 0; base2 < NPTS; base2 += 64) {
      int i = base2 + lane;
      float xx = xb[i * 3 + 0], yy = xb[i * 3 + 1], zz = xb[i * 3 + 2];
      float dq = d2e(xx, yy, zz, cx, cy, cz);
      bool m = dq < RR;
      unsigned long long mask = __ballot(m);
      if (mask) {
        if (firsti < 0) firsti = base2 + (__ffsll((unsigned long long)mask) - 1);
        int pos = cnt + (int)__popcll(mask & ((1ull << lane) - 1ull));
        if (m && pos < NSAMPLE) bl[pos] = i;
        cnt += (int)__popcll(mask);
        if (cnt >= NSAMPLE) break;
      }
    }
    for (int s = cnt + lane; s < NSAMPLE; s += 64) bl[s] = firsti;
    __builtin_amdgcn_s_waitcnt(0);

    // --- MLP, 2 samples in flight (R11-validated body)
    float vA = 0.f, vB = 0.f;
    int i0 = bl[0], i1 = bl[1];
    float fA = szb[(size_t)i0 * 64 + lane];
    float fB = szb[(size_t)i1 * 64 + lane];

    for (int s = 0; s < NSAMPLE; s += 2) {
      int sn0 = (s + 2 < NSAMPLE) ? s + 2 : s;
      int sn1 = (s + 3 < NSAMPLE) ? s + 3 : s;
      int in0 = bl[sn0], in1 = bl[sn1];
      float fn0 = szb[(size_t)in0 * 64 + lane];
      float fn1 = szb[(size_t)in1 * 64 + lane];

      float y0a = fmaxf(fA + hc, 0.f);
      float y0b = fmaxf(fB + hc, 0.f);
      yA[lane] = y0a;
      yB[lane] = y0b;
      float a0 = 0.f, a1 = 0.f, b0_ = 0.f, b1_ = 0.f;
#pragma unroll
      for (int i = 0; i < 16; i++) {
        float4 ya = yva[i], yb = yvb[i];
        float4 wv = w1v[i];
        a0 = fmaf(wv.x, ya.x, a0); a1 = fmaf(wv.y, ya.y, a1);
        a0 = fmaf(wv.z, ya.z, a0); a1 = fmaf(wv.w, ya.w, a1);
        b0_ = fmaf(wv.x, yb.x, b0_); b1_ = fmaf(wv.y, yb.y, b1_);
        b0_ = fmaf(wv.z, yb.z, b0_); b1_ = fmaf(wv.w, yb.w, b1_);
      }
      float y1a = fmaxf(fmaf(a0 + a1, sc1l, sh1l), 0.f);
      float y1b = fmaxf(fmaf(b0_ + b1_, sc1l, sh1l), 0.f);
      yA[lane] = y1a;
      yB[lane] = y1b;
      float c0 = 0.f, c1 = 0.f, e0 = 0.f, e1 = 0.f;
      float c0b = 0.f, c1b = 0.f, e0b = 0.f, e1b = 0.f;
#pragma unroll
      for (int i = 0; i < 16; i++) {
        float4 ya = yva[i], yb = yvb[i];
        float4 wa = w2av[i], wbv = w2bv[i];
        c0 = fmaf(wa.x, ya.x, c0); c1 = fmaf(wa.y, ya.y, c1);
        c0 = fmaf(wa.z, ya.z, c0); c1 = fmaf(wa.w, ya.w, c1);
        e0 = fmaf(wbv.x, ya.x, e0); e1 = fmaf(wbv.y, ya.y, e1);
        e0 = fmaf(wbv.z, ya.z, e0); e1 = fmaf(wbv.w, ya.w, e1);
        c0b = fmaf(wa.x, yb.x, c0b); c1b = fmaf(wa.y, yb.y, c1b);
        c0b = fmaf(wa.z, yb.z, c0b); c1b = fmaf(wa.w, yb.w, c1b);
        e0b = fmaf(wbv.x, yb.x, e0b); e1b = fmaf(wbv.y, yb.y, e1b);
        e0b = fmaf(wbv.z, yb.z, e0b); e1b = fmaf(wbv.w, yb.w, e1b);
      }
      float y2aA = fmaxf(fmaf(c0 + c1, sc2al, sh2al), 0.f);
      float y2bA = fmaxf(fmaf(e0 + e1, sc2bl, sh2bl), 0.f);
      float y2aB = fmaxf(fmaf(c0b + c1b, sc2al, sh2al), 0.f);
      float y2bB = fmaxf(fmaf(e0b + e1b, sc2bl, sh2bl), 0.f);
      vA = fmaxf(vA, fmaxf(y2aA, y2aB));
      vB = fmaxf(vB, fmaxf(y2bA, y2bB));
      fA = fn0;
      fB = fn1;
    }
    out_feat[((size_t)B0 * C2 + lane) * NPOINT + p] = vA;
    out_feat[((size_t)B0 * C2 + lane + 64) * NPOINT + p] = vB;
  }
}

// ---------------- prep: fold BN consts + zero padded counters ----------------
// wsp floats: [0..255] A4[o]={sc0*W0x,sc0*W0y,sc0*W0z,sh0}; [256..319] sc1;
// [320..383] sh1; [384..511] sc2; [512..639] sh2; [640..703] sc0
__global__ __launch_bounds__(128) void prep_kernel(
    const float* __restrict__ W0, const float* __restrict__ g0,
    const float* __restrict__ b0, const float* __restrict__ m0,
    const float* __restrict__ v0, const float* __restrict__ g1,
    const float* __restrict__ b1, const float* __restrict__ m1,
    const float* __restrict__ v1, const float* __restrict__ g2,
    const float* __restrict__ b2, const float* __restrict__ m2,
    const float* __restrict__ v2, float* __restrict__ wsp,
    int* __restrict__ ctr) {
  const int tid = threadIdx.x;
  for (int i = tid; i < 1024; i += 128) ctr[i] = 0;
  if (tid < 64) {
    float s0 = g0[tid] / sqrtf(v0[tid] + 1e-5f);
    wsp[4 * tid + 0] = s0 * W0[tid * K0 + 0];
    wsp[4 * tid + 1] = s0 * W0[tid * K0 + 1];
    wsp[4 * tid + 2] = s0 * W0[tid * K0 + 2];
    wsp[4 * tid + 3] = b0[tid] - m0[tid] * s0;
    wsp[640 + tid] = s0;
    float s1 = g1[tid] / sqrtf(v1[tid] + 1e-5f);
    wsp[256 + tid] = s1; wsp[320 + tid] = b1[tid] - m1[tid] * s1;
  }
  float s2 = g2[tid] / sqrtf(v2[tid] + 1e-5f);
  wsp[384 + tid] = s2; wsp[512 + tid] = b2[tid] - m2[tid] * s2;
}

extern "C" void kernel_launch(void* const* d_in, const int* in_sizes, int n_in,
                              void* d_out, int out_size, void* d_ws, size_t ws_size,
                              hipStream_t stream) {
  const float* xyz  = (const float*)d_in[0];
  const float* feat = (const float*)d_in[1];
  const float* W0 = (const float*)d_in[2];
  const float* g0 = (const float*)d_in[3];
  const float* b0 = (const float*)d_in[4];
  const float* m0 = (const float*)d_in[5];
  const float* v0 = (const float*)d_in[6];
  const float* W1 = (const float*)d_in[7];
  const float* g1 = (const float*)d_in[8];
  const float* b1 = (const float*)d_in[9];
  const float* m1 = (const float*)d_in[10];
  const float* v1 = (const float*)d_in[11];
  const float* W2 = (const float*)d_in[12];
  const float* g2 = (const float*)d_in[13];
  const float* b2 = (const float*)d_in[14];
  const float* m2 = (const float*)d_in[15];
  const float* v2 = (const float*)d_in[16];

  float* out = (float*)d_out;
  float* out_xyz  = out;                         // (8,2048,3)   = 49152
  float* out_feat = out + 49152;                 // (8,128,2048) = 2097152
  float* out_inds = out + 49152 + 2097152;       // (8,2048)     = 16384

  float* szp = (float*)d_ws;                                  // 16.8 MiB
  float* wsp = (float*)((char*)d_ws + 20971520);              // ~3 KiB
  int*   ctr = (int*)((char*)d_ws + 20975616);                // 1024 ints, padded

  hipLaunchKernelGGL(prep_kernel, dim3(1), dim3(128), 0, stream,
                     W0, g0, b0, m0, v0, g1, b1, m1, v1, g2, b2, m2, v2,
                     wsp, ctr);
  hipLaunchKernelGGL(mega_kernel, dim3(8 + 512), dim3(512), 0, stream,
                     xyz, feat, W0, W1, W2, wsp, szp, ctr,
                     out_xyz, out_feat, out_inds);
}

// Round 15
// 2867.700 us; speedup vs baseline: 1.0077x; 1.0077x over previous
//
#include <hip/hip_runtime.h>
#include <cstdint>
#include <cstddef>

#define BATCH   8
#define NPTS    8192
#define NPOINT  2048
#define NSAMPLE 64
#define K0      67      // 3 + 64 input channels
#define C2      128

// Exact-order squared distance, matching XLA/numpy: ((dx*dx + dy*dy) + dz*dz),
// separate mul/add (no FMA contraction), round-to-nearest f32.
__device__ __forceinline__ float d2e(float ax, float ay, float az,
                                     float bx, float by, float bz) {
#pragma clang fp contract(off)
  float dx = ax - bx;
  float dy = ay - by;
  float dz = az - bz;
  float t0 = dx * dx;
  float t1 = dy * dy;
  float t2 = dz * dz;
  return (t0 + t1) + t2;
}

// ---- wave64 reductions via DPP; result broadcast via readlane (uniform).
__device__ __forceinline__ float dpp_max_f32(float x) {
  int v;
  v = __builtin_amdgcn_update_dpp(__float_as_int(x), __float_as_int(x), 0xB1, 0xF, 0xF, false);
  x = fmaxf(x, __int_as_float(v));
  v = __builtin_amdgcn_update_dpp(__float_as_int(x), __float_as_int(x), 0x4E, 0xF, 0xF, false);
  x = fmaxf(x, __int_as_float(v));
  v = __builtin_amdgcn_update_dpp(__float_as_int(x), __float_as_int(x), 0x141, 0xF, 0xF, false);
  x = fmaxf(x, __int_as_float(v));
  v = __builtin_amdgcn_update_dpp(__float_as_int(x), __float_as_int(x), 0x140, 0xF, 0xF, false);
  x = fmaxf(x, __int_as_float(v));
  v = __builtin_amdgcn_update_dpp(__float_as_int(x), __float_as_int(x), 0x142, 0xA, 0xF, false);
  x = fmaxf(x, __int_as_float(v));
  v = __builtin_amdgcn_update_dpp(__float_as_int(x), __float_as_int(x), 0x143, 0xC, 0xF, false);
  x = fmaxf(x, __int_as_float(v));
  return __int_as_float(__builtin_amdgcn_readlane(__float_as_int(x), 63));
}

__device__ __forceinline__ int dpp_min_i32(int x) {
  int v;
  v = __builtin_amdgcn_update_dpp(x, x, 0xB1, 0xF, 0xF, false); x = min(x, v);
  v = __builtin_amdgcn_update_dpp(x, x, 0x4E, 0xF, 0xF, false); x = min(x, v);
  v = __builtin_amdgcn_update_dpp(x, x, 0x141, 0xF, 0xF, false); x = min(x, v);
  v = __builtin_amdgcn_update_dpp(x, x, 0x140, 0xF, 0xF, false); x = min(x, v);
  v = __builtin_amdgcn_update_dpp(x, x, 0x142, 0xA, 0xF, false); x = min(x, v);
  v = __builtin_amdgcn_update_dpp(x, x, 0x143, 0xC, 0xF, false); x = min(x, v);
  return __builtin_amdgcn_readlane(x, 63);
}

__device__ __forceinline__ void st_rel(int* p, int v) {
  __hip_atomic_store(p, v, __ATOMIC_RELEASE, __HIP_MEMORY_SCOPE_AGENT);
}
__device__ __forceinline__ int ld_acq(int* p) {
  return __hip_atomic_load(p, __ATOMIC_ACQUIRE, __HIP_MEMORY_SCOPE_AGENT);
}

// Padded counters (one per 256B line):
//   prog[b]  -> ctr[b * 64]        (b = 0..7)
//   zcnt[B]  -> ctr[512 + B * 64]  (B = 0..7)
#define PROG(b) (ctr + (b) * 64)
#define ZCNT(B) (ctr + 512 + (B) * 64)

// =============================================================================
// Mega kernel: blocks 0-7 = FPS producers (R9 body: NO per-iteration global
// stores — winners logged to LDS; centers flushed to out_xyz/out_inds in
// 32-entry chunks by wave 0 then release-published. This removes the
// cross-XCD store-invalidate latency from the producer's per-iteration
// barrier path, which R12-R14 showed costs ~45%). Blocks 8.. = workers:
// zfeat tiles, then per-wave {spin on prog, inline ball-query, MLP+pool}.
// Monotone frontier => deadlock-free; spins carry poll guards.
// =============================================================================
__global__ __launch_bounds__(512, 1) void mega_kernel(
    const float* __restrict__ xyz, const float* __restrict__ feat,
    const float* __restrict__ W0, const float* __restrict__ W1,
    const float* __restrict__ W2, const float* __restrict__ wsp,
    float* __restrict__ szp, int* __restrict__ ctr,
    float* __restrict__ out_xyz, float* __restrict__ out_feat,
    float* __restrict__ out_inds) {
  const int tid = threadIdx.x;
  const int lane = tid & 63;

  if (blockIdx.x < 8) {
    // ======================= FPS producer (R9 body) ========================
    const int b = blockIdx.x;
    const int w = tid >> 6;
    __shared__ float2 sxy[NPTS];
    __shared__ float  szl[NPTS];
    __shared__ unsigned short sslot[NPOINT];
    __shared__ unsigned long long wred[2][8] __attribute__((aligned(16)));

    const float* xb = xyz + (size_t)b * NPTS * 3;
    for (int k = 0; k < 16; k++) {
      int i = tid + k * 512;
      sxy[i] = make_float2(xb[i * 3 + 0], xb[i * 3 + 1]);
      szl[i] = xb[i * 3 + 2];
    }
    __syncthreads();

    const float2 q0xy = sxy[0];
    const float q0x = q0xy.x, q0y = q0xy.y, q0z = szl[0];

    const int base = tid * 16;
    float px[16], py[16], pz[16], dd[16];
#pragma unroll
    for (int j = 0; j < 16; j++) {
      float2 xy = sxy[base + j];
      px[j] = xy.x; py[j] = xy.y; pz[j] = szl[base + j];
      dd[j] = d2e(px[j], py[j], pz[j], q0x, q0y, q0z);
    }
    if (tid == 0) sslot[0] = 0;
    {
      float bv = dd[0]; int bj = base;
#pragma unroll
      for (int j = 1; j < 16; j++) {
        bool better = dd[j] > bv;
        bv = better ? dd[j] : bv;
        bj = better ? base + j : bj;
      }
      float vm = dpp_max_f32(bv);
      int ci = (bv == vm) ? bj : 0x7FFFFFFF;
      int widx = dpp_min_i32(ci);
      if (lane == 0)
        wred[0][w] = ((unsigned long long)(~__float_as_uint(vm)) << 32) | (unsigned)widx;
    }
    __syncthreads();

    for (int t = 1; t < NPOINT; ++t) {
      const ulonglong2* wv = (const ulonglong2*)wred[(t - 1) & 1];
      ulonglong2 p0 = wv[0], p1 = wv[1], p2 = wv[2], p3 = wv[3];
      unsigned long long g0 = (p0.y < p0.x) ? p0.y : p0.x;
      unsigned long long g1 = (p1.y < p1.x) ? p1.y : p1.x;
      unsigned long long g2 = (p2.y < p2.x) ? p2.y : p2.x;
      unsigned long long g3 = (p3.y < p3.x) ? p3.y : p3.x;
      g0 = (g1 < g0) ? g1 : g0; g2 = (g3 < g2) ? g3 : g2;
      g0 = (g2 < g0) ? g2 : g0;
      const int nxt = (int)(g0 & 0xFFFFFFFFu);
      const float2 qxy = sxy[nxt];
      const float qx = qxy.x, qy = qxy.y, qz = szl[nxt];
      if (tid == 0) sslot[t] = (unsigned short)nxt;

      float d0 = d2e(px[0], py[0], pz[0], qx, qy, qz);
      dd[0] = fminf(dd[0], d0);
      float bv = dd[0]; int bj = base;
#pragma unroll
      for (int j = 1; j < 16; j++) {
        float d = d2e(px[j], py[j], pz[j], qx, qy, qz);
        dd[j] = fminf(dd[j], d);
        bool better = dd[j] > bv;
        bv = better ? dd[j] : bv;
        bj = better ? base + j : bj;
      }
      float vm = dpp_max_f32(bv);
      int ci = (bv == vm) ? bj : 0x7FFFFFFF;
      int widx = dpp_min_i32(ci);
      if (lane == 0)
        wred[t & 1][w] = ((unsigned long long)(~__float_as_uint(vm)) << 32) | (unsigned)widx;

      // chunked flush: wave 0 writes the last 32 centers, then publishes.
      if ((t & 31) == 31 && w == 0) {
        if (lane < 32) {
          int e = t - 31 + lane;
          int o = (int)sslot[e];
          float2 xy = sxy[o];
          out_inds[b * NPOINT + e] = (float)o;
          out_xyz[((size_t)b * NPOINT + e) * 3 + 0] = xy.x;
          out_xyz[((size_t)b * NPOINT + e) * 3 + 1] = xy.y;
          out_xyz[((size_t)b * NPOINT + e) * 3 + 2] = szl[o];
        }
        if (lane == 0) st_rel(PROG(b), t + 1);   // vmcnt drain orders flush
      }
      __syncthreads();
    }
    return;
  }

  // =========================== worker block ================================
  const int wb = blockIdx.x - 8;       // 0..511
  const int w8 = tid >> 6;             // wave 0..7
  __shared__ float ftile[64][64];
  __shared__ float sxyzt[192];
  __shared__ float ylds2[8][2][64];
  __shared__ int   blds8[8][64];

  // ---- phase A: two zfeat tiles (independent of FPS)
  for (int tt = 0; tt < 2; tt++) {
    const int bt = wb * 2 + tt;
    const int B = bt >> 7, nt = bt & 127;
    const float* fb = feat + (size_t)B * 64 * NPTS + (size_t)nt * 64;
    for (int r = w8; r < 64; r += 8)
      ftile[r][lane] = fb[(size_t)r * NPTS + lane];
    if (tid < 192)
      sxyzt[tid] = xyz[((size_t)B * NPTS + (size_t)nt * 64) * 3 + tid];
    float w0x = W0[lane * K0 + 0], w0y = W0[lane * K0 + 1], w0z = W0[lane * K0 + 2];
    float wf[64];
#pragma unroll
    for (int i = 0; i < 64; i++) wf[i] = W0[lane * K0 + 3 + i];
    const float s0 = wsp[640 + lane];
    __syncthreads();
    float* ob = szp + ((size_t)B * NPTS + (size_t)nt * 64) * 64;
    for (int u = w8; u < 64; u += 8) {
      float acc = w0x * sxyzt[u * 3 + 0] + w0y * sxyzt[u * 3 + 1] + w0z * sxyzt[u * 3 + 2];
#pragma unroll
      for (int i = 0; i < 64; i++) acc = fmaf(wf[i], ftile[i][u], acc);
      ob[(size_t)u * 64 + lane] = acc * s0;
    }
    __syncthreads();
    if (tid == 0) {
      __threadfence();                               // all block stores -> L2 wb
      __hip_atomic_fetch_add(ZCNT(B), 1, __ATOMIC_RELEASE, __HIP_MEMORY_SCOPE_AGENT);
    }
  }

  // ---- phase B: wait until this batch's szp is fully built
  const int B0 = wb >> 6;              // 64 worker blocks per batch
  {
    int guard = 0;
    while (ld_acq(ZCNT(B0)) < 128 && ++guard < (1 << 18))
      __builtin_amdgcn_s_sleep(32);
  }
  __syncthreads();

  // ---- phase C: per-wave {spin, ball-query, MLP}
  float4 w1v[16], w2av[16], w2bv[16];
  const float4* W1r = (const float4*)(W1 + lane * 64);
  const float4* W2ar = (const float4*)(W2 + lane * 64);
  const float4* W2br = (const float4*)(W2 + (lane + 64) * 64);
#pragma unroll
  for (int i = 0; i < 16; i++) { w1v[i] = W1r[i]; w2av[i] = W2ar[i]; w2bv[i] = W2br[i]; }
  const float4 Aq = ((const float4*)wsp)[lane];
  const float sc1l = wsp[256 + lane], sh1l = wsp[320 + lane];
  const float sc2al = wsp[384 + lane], sh2al = wsp[512 + lane];
  const float sc2bl = wsp[448 + lane], sh2bl = wsp[576 + lane];
  const float RR = (float)(0.4 * 0.4);

  float* yA = ylds2[w8][0];
  float* yB = ylds2[w8][1];
  const float4* yva = (const float4*)yA;
  const float4* yvb = (const float4*)yB;
  int* bl = blds8[w8];
  const float* xb = xyz + (size_t)B0 * NPTS * 3;
  const float* szb = szp + (size_t)B0 * NPTS * 64;

  for (int qi = 0; qi < 4; qi++) {
    const int q = wb * 32 + qi * 8 + w8;
    const int p = q & 2047;

    {
      int guard = 0;
      while (ld_acq(PROG(B0)) < p + 1 && ++guard < (1 << 18))
        __builtin_amdgcn_s_sleep(32);
    }
    const float cx = out_xyz[(size_t)q * 3 + 0];
    const float cy = out_xyz[(size_t)q * 3 + 1];
    const float cz = out_xyz[(size_t)q * 3 + 2];
    const float hc = Aq.w - (Aq.x * cx + Aq.y * cy + Aq.z * cz);

    // --- inline ball query (exact logic of validated ballq kernel)
    int cnt = 0, firsti = -1;
    for (int base2 = 0; base2 < NPTS; base2 += 64) {
      int i = base2 + lane;
      float xx = xb[i * 3 + 0], yy = xb[i * 3 + 1], zz = xb[i * 3 + 2];
      float dq = d2e(xx, yy, zz, cx, cy, cz);
      bool m = dq < RR;
      unsigned long long mask = __ballot(m);
      if (mask) {
        if (firsti < 0) firsti = base2 + (__ffsll((unsigned long long)mask) - 1);
        int pos = cnt + (int)__popcll(mask & ((1ull << lane) - 1ull));
        if (m && pos < NSAMPLE) bl[pos] = i;
        cnt += (int)__popcll(mask);
        if (cnt >= NSAMPLE) break;
      }
    }
    for (int s = cnt + lane; s < NSAMPLE; s += 64) bl[s] = firsti;
    __builtin_amdgcn_s_waitcnt(0);

    // --- MLP, 2 samples in flight (R11-validated body)
    float vA = 0.f, vB = 0.f;
    int i0 = bl[0], i1 = bl[1];
    float fA = szb[(size_t)i0 * 64 + lane];
    float fB = szb[(size_t)i1 * 64 + lane];

    for (int s = 0; s < NSAMPLE; s += 2) {
      int sn0 = (s + 2 < NSAMPLE) ? s + 2 : s;
      int sn1 = (s + 3 < NSAMPLE) ? s + 3 : s;
      int in0 = bl[sn0], in1 = bl[sn1];
      float fn0 = szb[(size_t)in0 * 64 + lane];
      float fn1 = szb[(size_t)in1 * 64 + lane];

      float y0a = fmaxf(fA + hc, 0.f);
      float y0b = fmaxf(fB + hc, 0.f);
      yA[lane] = y0a;
      yB[lane] = y0b;
      float a0 = 0.f, a1 = 0.f, b0_ = 0.f, b1_ = 0.f;
#pragma unroll
      for (int i = 0; i < 16; i++) {
        float4 ya = yva[i], yb = yvb[i];
        float4 wv = w1v[i];
        a0 = fmaf(wv.x, ya.x, a0); a1 = fmaf(wv.y, ya.y, a1);
        a0 = fmaf(wv.z, ya.z, a0); a1 = fmaf(wv.w, ya.w, a1);
        b0_ = fmaf(wv.x, yb.x, b0_); b1_ = fmaf(wv.y, yb.y, b1_);
        b0_ = fmaf(wv.z, yb.z, b0_); b1_ = fmaf(wv.w, yb.w, b1_);
      }
      float y1a = fmaxf(fmaf(a0 + a1, sc1l, sh1l), 0.f);
      float y1b = fmaxf(fmaf(b0_ + b1_, sc1l, sh1l), 0.f);
      yA[lane] = y1a;
      yB[lane] = y1b;
      float c0 = 0.f, c1 = 0.f, e0 = 0.f, e1 = 0.f;
      float c0b = 0.f, c1b = 0.f, e0b = 0.f, e1b = 0.f;
#pragma unroll
      for (int i = 0; i < 16; i++) {
        float4 ya = yva[i], yb = yvb[i];
        float4 wa = w2av[i], wbv = w2bv[i];
        c0 = fmaf(wa.x, ya.x, c0); c1 = fmaf(wa.y, ya.y, c1);
        c0 = fmaf(wa.z, ya.z, c0); c1 = fmaf(wa.w, ya.w, c1);
        e0 = fmaf(wbv.x, ya.x, e0); e1 = fmaf(wbv.y, ya.y, e1);
        e0 = fmaf(wbv.z, ya.z, e0); e1 = fmaf(wbv.w, ya.w, e1);
        c0b = fmaf(wa.x, yb.x, c0b); c1b = fmaf(wa.y, yb.y, c1b);
        c0b = fmaf(wa.z, yb.z, c0b); c1b = fmaf(wa.w, yb.w, c1b);
        e0b = fmaf(wbv.x, yb.x, e0b); e1b = fmaf(wbv.y, yb.y, e1b);
        e0b = fmaf(wbv.z, yb.z, e0b); e1b = fmaf(wbv.w, yb.w, e1b);
      }
      float y2aA = fmaxf(fmaf(c0 + c1, sc2al, sh2al), 0.f);
      float y2bA = fmaxf(fmaf(e0 + e1, sc2bl, sh2bl), 0.f);
      float y2aB = fmaxf(fmaf(c0b + c1b, sc2al, sh2al), 0.f);
      float y2bB = fmaxf(fmaf(e0b + e1b, sc2bl, sh2bl), 0.f);
      vA = fmaxf(vA, fmaxf(y2aA, y2aB));
      vB = fmaxf(vB, fmaxf(y2bA, y2bB));
      fA = fn0;
      fB = fn1;
    }
    out_feat[((size_t)B0 * C2 + lane) * NPOINT + p] = vA;
    out_feat[((size_t)B0 * C2 + lane + 64) * NPOINT + p] = vB;
  }
}

// ---------------- prep: fold BN consts + zero padded counters ----------------
__global__ __launch_bounds__(128) void prep_kernel(
    const float* __restrict__ W0, const float* __restrict__ g0,
    const float* __restrict__ b0, const float* __restrict__ m0,
    const float* __restrict__ v0, const float* __restrict__ g1,
    const float* __restrict__ b1, const float* __restrict__ m1,
    const float* __restrict__ v1, const float* __restrict__ g2,
    const float* __restrict__ b2, const float* __restrict__ m2,
    const float* __restrict__ v2, float* __restrict__ wsp,
    int* __restrict__ ctr) {
  const int tid = threadIdx.x;
  for (int i = tid; i < 1024; i += 128) ctr[i] = 0;
  if (tid < 64) {
    float s0 = g0[tid] / sqrtf(v0[tid] + 1e-5f);
    wsp[4 * tid + 0] = s0 * W0[tid * K0 + 0];
    wsp[4 * tid + 1] = s0 * W0[tid * K0 + 1];
    wsp[4 * tid + 2] = s0 * W0[tid * K0 + 2];
    wsp[4 * tid + 3] = b0[tid] - m0[tid] * s0;
    wsp[640 + tid] = s0;
    float s1 = g1[tid] / sqrtf(v1[tid] + 1e-5f);
    wsp[256 + tid] = s1; wsp[320 + tid] = b1[tid] - m1[tid] * s1;
  }
  float s2 = g2[tid] / sqrtf(v2[tid] + 1e-5f);
  wsp[384 + tid] = s2; wsp[512 + tid] = b2[tid] - m2[tid] * s2;
}

extern "C" void kernel_launch(void* const* d_in, const int* in_sizes, int n_in,
                              void* d_out, int out_size, void* d_ws, size_t ws_size,
                              hipStream_t stream) {
  const float* xyz  = (const float*)d_in[0];
  const float* feat = (const float*)d_in[1];
  const float* W0 = (const float*)d_in[2];
  const float* g0 = (const float*)d_in[3];
  const float* b0 = (const float*)d_in[4];
  const float* m0 = (const float*)d_in[5];
  const float* v0 = (const float*)d_in[6];
  const float* W1 = (const float*)d_in[7];
  const float* g1 = (const float*)d_in[8];
  const float* b1 = (const float*)d_in[9];
  const float* m1 = (const float*)d_in[10];
  const float* v1 = (const float*)d_in[11];
  const float* W2 = (const float*)d_in[12];
  const float* g2 = (const float*)d_in[13];
  const float* b2 = (const float*)d_in[14];
  const float* m2 = (const float*)d_in[15];
  const float* v2 = (const float*)d_in[16];

  float* out = (float*)d_out;
  float* out_xyz  = out;                         // (8,2048,3)   = 49152
  float* out_feat = out + 49152;                 // (8,128,2048) = 2097152
  float* out_inds = out + 49152 + 2097152;       // (8,2048)     = 16384

  float* szp = (float*)d_ws;                                  // 16.8 MiB
  float* wsp = (float*)((char*)d_ws + 20971520);              // ~3 KiB
  int*   ctr = (int*)((char*)d_ws + 20975616);                // 1024 ints, padded

  hipLaunchKernelGGL(prep_kernel, dim3(1), dim3(128), 0, stream,
                     W0, g0, b0, m0, v0, g1, b1, m1, v1, g2, b2, m2, v2,
                     wsp, ctr);
  hipLaunchKernelGGL(mega_kernel, dim3(8 + 512), dim3(512), 0, stream,
                     xyz, feat, W0, W1, W2, wsp, szp, ctr,
                     out_xyz, out_feat, out_inds);
}

// Round 16
// 2845.374 us; speedup vs baseline: 1.0156x; 1.0078x over previous
//
#include <hip/hip_runtime.h>
#include <cstdint>
#include <cstddef>

#define BATCH   8
#define NPTS    8192
#define NPOINT  2048
#define NSAMPLE 64
#define K0      67      // 3 + 64 input channels
#define C2      128

typedef float v2f __attribute__((ext_vector_type(2)));

// Exact-order squared distance, matching XLA/numpy: ((dx*dx + dy*dy) + dz*dz),
// separate mul/add (no FMA contraction), round-to-nearest f32.
__device__ __forceinline__ float d2e(float ax, float ay, float az,
                                     float bx, float by, float bz) {
#pragma clang fp contract(off)
  float dx = ax - bx;
  float dy = ay - by;
  float dz = az - bz;
  float t0 = dx * dx;
  float t1 = dy * dy;
  float t2 = dz * dz;
  return (t0 + t1) + t2;
}

// ---- wave64 reductions via DPP; result broadcast via readlane (uniform).
__device__ __forceinline__ float dpp_max_f32(float x) {
  int v;
  v = __builtin_amdgcn_update_dpp(__float_as_int(x), __float_as_int(x), 0xB1, 0xF, 0xF, false);
  x = fmaxf(x, __int_as_float(v));
  v = __builtin_amdgcn_update_dpp(__float_as_int(x), __float_as_int(x), 0x4E, 0xF, 0xF, false);
  x = fmaxf(x, __int_as_float(v));
  v = __builtin_amdgcn_update_dpp(__float_as_int(x), __float_as_int(x), 0x141, 0xF, 0xF, false);
  x = fmaxf(x, __int_as_float(v));
  v = __builtin_amdgcn_update_dpp(__float_as_int(x), __float_as_int(x), 0x140, 0xF, 0xF, false);
  x = fmaxf(x, __int_as_float(v));
  v = __builtin_amdgcn_update_dpp(__float_as_int(x), __float_as_int(x), 0x142, 0xA, 0xF, false);
  x = fmaxf(x, __int_as_float(v));
  v = __builtin_amdgcn_update_dpp(__float_as_int(x), __float_as_int(x), 0x143, 0xC, 0xF, false);
  x = fmaxf(x, __int_as_float(v));
  return __int_as_float(__builtin_amdgcn_readlane(__float_as_int(x), 63));
}

__device__ __forceinline__ int dpp_min_i32(int x) {
  int v;
  v = __builtin_amdgcn_update_dpp(x, x, 0xB1, 0xF, 0xF, false); x = min(x, v);
  v = __builtin_amdgcn_update_dpp(x, x, 0x4E, 0xF, 0xF, false); x = min(x, v);
  v = __builtin_amdgcn_update_dpp(x, x, 0x141, 0xF, 0xF, false); x = min(x, v);
  v = __builtin_amdgcn_update_dpp(x, x, 0x140, 0xF, 0xF, false); x = min(x, v);
  v = __builtin_amdgcn_update_dpp(x, x, 0x142, 0xA, 0xF, false); x = min(x, v);
  v = __builtin_amdgcn_update_dpp(x, x, 0x143, 0xC, 0xF, false); x = min(x, v);
  return __builtin_amdgcn_readlane(x, 63);
}

// ---------------- FPS: brute-force update (packed f32), 1 barrier/iter -------
// R9 structure (measured 2014 us, VALU-issue-bound). Thread tid owns 16
// contiguous points as 8 float2 pairs; the d2e+fmin update compiles to
// v_pk_add/mul_f32 (two IEEE f32 ops per instr, bit-identical rounding, same
// per-element op order -> dd bit-exact). Tie-break scan stays scalar
// strict-> ascending (= first index). DPP reduce + u64 key across waves; no
// in-loop global stores; winners logged to u16 LDS; batched writeback.
__global__ __launch_bounds__(512) void fps_kernel(const float* __restrict__ xyz,
                                                  float* __restrict__ out_xyz,
                                                  float* __restrict__ out_inds) {
  const int b = blockIdx.x;
  const int tid = threadIdx.x;
  const int lane = tid & 63, w = tid >> 6;

  __shared__ float2 sxy[NPTS];                  // original order
  __shared__ float  szl[NPTS];
  __shared__ unsigned short sslot[NPOINT];      // winner index per t
  __shared__ unsigned long long wred[2][8] __attribute__((aligned(16)));

  const float* xb = xyz + (size_t)b * NPTS * 3;

  // --- coalesced stage to LDS
  for (int k = 0; k < 16; k++) {
    int i = tid + k * 512;
    sxy[i] = make_float2(xb[i * 3 + 0], xb[i * 3 + 1]);
    szl[i] = xb[i * 3 + 2];
  }
  __syncthreads();

  const float2 q0xy = sxy[0];
  const float q0x = q0xy.x, q0y = q0xy.y, q0z = szl[0];

  // --- own 16 contiguous points as 8 packed pairs, init dd (packed, exact)
  const int base = tid * 16;
  v2f px2[8], py2[8], pz2[8], dd2[8];
  {
#pragma clang fp contract(off)
#pragma unroll
    for (int k = 0; k < 8; k++) {
      float2 a = sxy[base + 2 * k];
      float2 c = sxy[base + 2 * k + 1];
      px2[k] = (v2f){a.x, c.x};
      py2[k] = (v2f){a.y, c.y};
      pz2[k] = (v2f){szl[base + 2 * k], szl[base + 2 * k + 1]};
      v2f dx = px2[k] - q0x;
      v2f dy = py2[k] - q0y;
      v2f dz = pz2[k] - q0z;
      v2f t0 = dx * dx;
      v2f t1 = dy * dy;
      v2f t2 = dz * dz;
      dd2[k] = (t0 + t1) + t2;
    }
  }
  if (tid == 0) sslot[0] = 0;

  // --- initial scan (strict >, ascending = first index) + DPP reduce
  {
    float bv = -1.f; int bj = base;
#pragma unroll
    for (int k = 0; k < 8; k++) {
      float d0 = dd2[k].x, d1 = dd2[k].y;
      bool c0 = d0 > bv; bv = c0 ? d0 : bv; bj = c0 ? base + 2 * k : bj;
      bool c1 = d1 > bv; bv = c1 ? d1 : bv; bj = c1 ? base + 2 * k + 1 : bj;
    }
    float vm = dpp_max_f32(bv);
    int ci = (bv == vm) ? bj : 0x7FFFFFFF;
    int widx = dpp_min_i32(ci);
    if (lane == 0)
      wred[0][w] = ((unsigned long long)(~__float_as_uint(vm)) << 32) | (unsigned)widx;
  }
  __syncthreads();

  for (int t = 1; t < NPOINT; ++t) {
    // --- global winner = min of 8 wave keys (vectorized broadcast reads)
    const ulonglong2* wv = (const ulonglong2*)wred[(t - 1) & 1];
    ulonglong2 p0 = wv[0], p1 = wv[1], p2 = wv[2], p3 = wv[3];
    unsigned long long g0 = (p0.y < p0.x) ? p0.y : p0.x;
    unsigned long long g1 = (p1.y < p1.x) ? p1.y : p1.x;
    unsigned long long g2 = (p2.y < p2.x) ? p2.y : p2.x;
    unsigned long long g3 = (p3.y < p3.x) ? p3.y : p3.x;
    g0 = (g1 < g0) ? g1 : g0; g2 = (g3 < g2) ? g3 : g2;
    g0 = (g2 < g0) ? g2 : g0;
    const int nxt = (int)(g0 & 0xFFFFFFFFu);
    const float2 qxy = sxy[nxt];
    const float qx = qxy.x, qy = qxy.y, qz = szl[nxt];
    if (tid == 0) sslot[t] = (unsigned short)nxt;

    // --- packed straight-line update + scalar tie-aware scan (no branches)
    float bv = -1.f; int bj = base;
    {
#pragma clang fp contract(off)
#pragma unroll
      for (int k = 0; k < 8; k++) {
        v2f dx = px2[k] - qx;
        v2f dy = py2[k] - qy;
        v2f dz = pz2[k] - qz;
        v2f t0 = dx * dx;
        v2f t1 = dy * dy;
        v2f t2 = dz * dz;
        v2f d = (t0 + t1) + t2;
        v2f nd;
        nd.x = fminf(dd2[k].x, d.x);
        nd.y = fminf(dd2[k].y, d.y);
        dd2[k] = nd;
        bool c0 = nd.x > bv; bv = c0 ? nd.x : bv; bj = c0 ? base + 2 * k : bj;
        bool c1 = nd.y > bv; bv = c1 ? nd.y : bv; bj = c1 ? base + 2 * k + 1 : bj;
      }
    }
    float vm = dpp_max_f32(bv);
    int ci = (bv == vm) ? bj : 0x7FFFFFFF;
    int widx = dpp_min_i32(ci);
    if (lane == 0)
      wred[t & 1][w] = ((unsigned long long)(~__float_as_uint(vm)) << 32) | (unsigned)widx;
    __syncthreads();
  }

  // --- parallel writeback: inds + xyz from recorded winner indices
  for (int t = tid; t < NPOINT; t += 512) {
    int o = (int)sslot[t];
    float2 xy = sxy[o];
    out_inds[b * NPOINT + t] = (float)o;
    out_xyz[((size_t)b * NPOINT + t) * 3 + 0] = xy.x;
    out_xyz[((size_t)b * NPOINT + t) * 3 + 1] = xy.y;
    out_xyz[((size_t)b * NPOINT + t) * 3 + 2] = szl[o];
  }
}

// ---------------- prep: fold BN into per-channel consts ----------------------
// wsp floats: [0..255] A4[o]={sc0*W0x,sc0*W0y,sc0*W0z,sh0}; [256..319] sc1;
// [320..383] sh1; [384..511] sc2; [512..639] sh2; [640..703] sc0
__global__ __launch_bounds__(128) void prep_kernel(
    const float* __restrict__ W0, const float* __restrict__ g0,
    const float* __restrict__ b0, const float* __restrict__ m0,
    const float* __restrict__ v0, const float* __restrict__ g1,
    const float* __restrict__ b1, const float* __restrict__ m1,
    const float* __restrict__ v1, const float* __restrict__ g2,
    const float* __restrict__ b2, const float* __restrict__ m2,
    const float* __restrict__ v2, float* __restrict__ wsp) {
  const int tid = threadIdx.x;
  if (tid < 64) {
    float s0 = g0[tid] / sqrtf(v0[tid] + 1e-5f);
    wsp[4 * tid + 0] = s0 * W0[tid * K0 + 0];
    wsp[4 * tid + 1] = s0 * W0[tid * K0 + 1];
    wsp[4 * tid + 2] = s0 * W0[tid * K0 + 2];
    wsp[4 * tid + 3] = b0[tid] - m0[tid] * s0;
    wsp[640 + tid] = s0;
    float s1 = g1[tid] / sqrtf(v1[tid] + 1e-5f);
    wsp[256 + tid] = s1; wsp[320 + tid] = b1[tid] - m1[tid] * s1;
  }
  float s2 = g2[tid] / sqrtf(v2[tid] + 1e-5f);
  wsp[384 + tid] = s2; wsp[512 + tid] = b2[tid] - m2[tid] * s2;
}

// ---------------- zfeat: per-point L0 linear part ----------------------------
// szp[n][o] = sc0[o] * ( W0[o][0:3] . p_xyz + W0[o][3:67] . feat[:,n] )
__global__ __launch_bounds__(256) void zfeat_kernel(const float* __restrict__ xyz,
                                                    const float* __restrict__ feat,
                                                    const float* __restrict__ W0,
                                                    const float* __restrict__ wsp,
                                                    float* __restrict__ szp) {
  __shared__ float ftile[64][64];   // [c][u] - reads are wave-uniform
  __shared__ float sxyz[192];
  const int bt = blockIdx.x;        // b*128 + nt
  const int b = bt >> 7, nt = bt & 127;
  const int tid = threadIdx.x;
  const int lane = tid & 63, w = tid >> 6;

  const float* fb = feat + (size_t)b * 64 * NPTS + (size_t)nt * 64;
#pragma unroll
  for (int r = w; r < 64; r += 4)
    ftile[r][lane] = fb[(size_t)r * NPTS + lane];
  if (tid < 192)
    sxyz[tid] = xyz[((size_t)b * NPTS + (size_t)nt * 64) * 3 + tid];

  float w0x = W0[lane * K0 + 0], w0y = W0[lane * K0 + 1], w0z = W0[lane * K0 + 2];
  float wf[64];
#pragma unroll
  for (int i = 0; i < 64; i++) wf[i] = W0[lane * K0 + 3 + i];
  const float s0 = wsp[640 + lane];
  __syncthreads();

  float* ob = szp + ((size_t)b * NPTS + (size_t)nt * 64) * 64;
  for (int u = w; u < 64; u += 4) {
    float acc = w0x * sxyz[u * 3 + 0] + w0y * sxyz[u * 3 + 1] + w0z * sxyz[u * 3 + 2];
#pragma unroll
    for (int i = 0; i < 64; i++) acc = fmaf(wf[i], ftile[i][u], acc);
    ob[(size_t)u * 64 + lane] = acc * s0;
  }
}

// ---------------- ball query: one wave per query point -----------------------
__global__ __launch_bounds__(256) void ballq_kernel(const float* __restrict__ xyz,
                                                    const float* __restrict__ new_xyz,
                                                    int* __restrict__ ball) {
  const int lane = threadIdx.x & 63;
  const int q = blockIdx.x * 4 + (threadIdx.x >> 6);
  const int b = q >> 11;
  const float RR = (float)(0.4 * 0.4);
  const float cx = new_xyz[(size_t)q * 3 + 0];
  const float cy = new_xyz[(size_t)q * 3 + 1];
  const float cz = new_xyz[(size_t)q * 3 + 2];
  const float* xb = xyz + (size_t)b * NPTS * 3;
  int cnt = 0, firsti = -1;
  for (int base = 0; base < NPTS; base += 64) {
    int i = base + lane;
    float xx = xb[i * 3 + 0], yy = xb[i * 3 + 1], zz = xb[i * 3 + 2];
    float d2 = d2e(xx, yy, zz, cx, cy, cz);
    bool m = d2 < RR;
    unsigned long long mask = __ballot(m);
    if (mask) {
      if (firsti < 0) firsti = base + (__ffsll((unsigned long long)mask) - 1);
      int pos = cnt + (int)__popcll(mask & ((1ull << lane) - 1ull));
      if (m && pos < NSAMPLE) ball[(size_t)q * NSAMPLE + pos] = i;
      cnt += (int)__popcll(mask);
      if (cnt >= NSAMPLE) break;
    }
  }
  for (int s = cnt + lane; s < NSAMPLE; s += 64)
    ball[(size_t)q * NSAMPLE + s] = firsti;
}

// ---------------- MLP L1/L2 + max-pool: lane = channel, 3-deep prefetch ------
// Single-sample body (R9); szp gather prefetched 3 samples ahead (~2300 cy of
// cover vs ~900 cy L3/HBM latency at 2 waves/SIMD — the R11 1-pair lookahead
// barely missed, which is why LDS pipelining alone was neutral).
#define QPW 4
__global__ __launch_bounds__(256, 2) void mlp_kernel(
    const float* __restrict__ szp, const int* __restrict__ ball,
    const float* __restrict__ new_xyz, const float* __restrict__ W1,
    const float* __restrict__ W2, const float* __restrict__ wsp,
    float* __restrict__ out_feat) {
  __shared__ float ylds[4][64];
  __shared__ int   blds[4][64];
  const int tid = threadIdx.x;
  const int lane = tid & 63, wid = tid >> 6;

  float4 w1v[16], w2av[16], w2bv[16];
  const float4* W1r = (const float4*)(W1 + lane * 64);
  const float4* W2ar = (const float4*)(W2 + lane * 64);
  const float4* W2br = (const float4*)(W2 + (lane + 64) * 64);
#pragma unroll
  for (int i = 0; i < 16; i++) { w1v[i] = W1r[i]; w2av[i] = W2ar[i]; w2bv[i] = W2br[i]; }
  const float4 A = ((const float4*)wsp)[lane];
  const float sc1l = wsp[256 + lane], sh1l = wsp[320 + lane];
  const float sc2al = wsp[384 + lane], sh2al = wsp[512 + lane];
  const float sc2bl = wsp[448 + lane], sh2bl = wsp[576 + lane];

  for (int qi = 0; qi < QPW; qi++) {
    const int q = blockIdx.x * (4 * QPW) + qi * 4 + wid;
    const int b = q >> 11, p = q & 2047;

    const float cx = new_xyz[(size_t)q * 3 + 0];
    const float cy = new_xyz[(size_t)q * 3 + 1];
    const float cz = new_xyz[(size_t)q * 3 + 2];
    const float hc = A.w - (A.x * cx + A.y * cy + A.z * cz);

    blds[wid][lane] = ball[(size_t)q * NSAMPLE + lane];
    const float* szb = szp + (size_t)b * NPTS * 64;
    __builtin_amdgcn_s_waitcnt(0);   // vm+lgkm: blds visible to own wave

    float vA = 0.f, vB = 0.f;
    int i0 = blds[wid][0], i1 = blds[wid][1], i2 = blds[wid][2];
    float f0 = szb[(size_t)i0 * 64 + lane];
    float f1 = szb[(size_t)i1 * 64 + lane];
    float f2 = szb[(size_t)i2 * 64 + lane];
    const float4* yv = (const float4*)ylds[wid];

    for (int s = 0; s < NSAMPLE; s++) {
      int sn = (s + 3 < NSAMPLE) ? s + 3 : NSAMPLE - 1;
      int idxn = blds[wid][sn];
      float fn = szb[(size_t)idxn * 64 + lane];

      float y0 = fmaxf(f0 + hc, 0.f);
      ylds[wid][lane] = y0;
      float a0 = 0.f, a1 = 0.f, a2 = 0.f, a3 = 0.f;
#pragma unroll
      for (int i = 0; i < 16; i++) {
        float4 y = yv[i];
        a0 = fmaf(w1v[i].x, y.x, a0);
        a1 = fmaf(w1v[i].y, y.y, a1);
        a2 = fmaf(w1v[i].z, y.z, a2);
        a3 = fmaf(w1v[i].w, y.w, a3);
      }
      float y1 = fmaxf(fmaf((a0 + a1) + (a2 + a3), sc1l, sh1l), 0.f);
      ylds[wid][lane] = y1;
      float c0 = 0.f, c1 = 0.f, c2 = 0.f, c3 = 0.f;
      float e0 = 0.f, e1 = 0.f, e2 = 0.f, e3 = 0.f;
#pragma unroll
      for (int i = 0; i < 16; i++) {
        float4 y = yv[i];
        c0 = fmaf(w2av[i].x, y.x, c0);
        c1 = fmaf(w2av[i].y, y.y, c1);
        c2 = fmaf(w2av[i].z, y.z, c2);
        c3 = fmaf(w2av[i].w, y.w, c3);
        e0 = fmaf(w2bv[i].x, y.x, e0);
        e1 = fmaf(w2bv[i].y, y.y, e1);
        e2 = fmaf(w2bv[i].z, y.z, e2);
        e3 = fmaf(w2bv[i].w, y.w, e3);
      }
      float y2a = fmaxf(fmaf((c0 + c1) + (c2 + c3), sc2al, sh2al), 0.f);
      float y2b = fmaxf(fmaf((e0 + e1) + (e2 + e3), sc2bl, sh2bl), 0.f);
      vA = fmaxf(vA, y2a);
      vB = fmaxf(vB, y2b);
      f0 = f1; f1 = f2; f2 = fn;
    }
    out_feat[((size_t)b * C2 + lane) * NPOINT + p] = vA;
    out_feat[((size_t)b * C2 + lane + 64) * NPOINT + p] = vB;
  }
}

extern "C" void kernel_launch(void* const* d_in, const int* in_sizes, int n_in,
                              void* d_out, int out_size, void* d_ws, size_t ws_size,
                              hipStream_t stream) {
  const float* xyz  = (const float*)d_in[0];
  const float* feat = (const float*)d_in[1];
  const float* W0 = (const float*)d_in[2];
  const float* g0 = (const float*)d_in[3];
  const float* b0 = (const float*)d_in[4];
  const float* m0 = (const float*)d_in[5];
  const float* v0 = (const float*)d_in[6];
  const float* W1 = (const float*)d_in[7];
  const float* g1 = (const float*)d_in[8];
  const float* b1 = (const float*)d_in[9];
  const float* m1 = (const float*)d_in[10];
  const float* v1 = (const float*)d_in[11];
  const float* W2 = (const float*)d_in[12];
  const float* g2 = (const float*)d_in[13];
  const float* b2 = (const float*)d_in[14];
  const float* m2 = (const float*)d_in[15];
  const float* v2 = (const float*)d_in[16];

  float* out = (float*)d_out;
  float* out_xyz  = out;                         // (8,2048,3)   = 49152
  float* out_feat = out + 49152;                 // (8,128,2048) = 2097152
  float* out_inds = out + 49152 + 2097152;       // (8,2048)     = 16384

  int*   ball = (int*)d_ws;                                      // 4 MiB
  float* szp  = (float*)((char*)d_ws + 4194304);                 // 16.8 MiB
  float* wsp  = (float*)((char*)d_ws + 20971520);                // ~3 KiB

  hipLaunchKernelGGL(prep_kernel, dim3(1), dim3(128), 0, stream,
                     W0, g0, b0, m0, v0, g1, b1, m1, v1, g2, b2, m2, v2, wsp);
  hipLaunchKernelGGL(zfeat_kernel, dim3(BATCH * (NPTS / 64)), dim3(256), 0, stream,
                     xyz, feat, W0, wsp, szp);
  hipLaunchKernelGGL(fps_kernel, dim3(BATCH), dim3(512), 0, stream,
                     xyz, out_xyz, out_inds);
  hipLaunchKernelGGL(ballq_kernel, dim3((BATCH * NPOINT) / 4), dim3(256), 0, stream,
                     xyz, out_xyz, ball);
  hipLaunchKernelGGL(mlp_kernel, dim3((BATCH * NPOINT) / (4 * QPW)), dim3(256), 0, stream,
                     szp, ball, out_xyz, W1, W2, wsp, out_feat);
}

// Round 17
// 2554.987 us; speedup vs baseline: 1.1310x; 1.1137x over previous
//
#include <hip/hip_runtime.h>
#include <cstdint>
#include <cstddef>

#define BATCH   8
#define NPTS    8192
#define NPOINT  2048
#define NSAMPLE 64
#define K0      67      // 3 + 64 input channels
#define C2      128

typedef float v2f __attribute__((ext_vector_type(2)));

// Exact-order squared distance, matching XLA/numpy: ((dx*dx + dy*dy) + dz*dz),
// separate mul/add (no FMA contraction), round-to-nearest f32.
__device__ __forceinline__ float d2e(float ax, float ay, float az,
                                     float bx, float by, float bz) {
#pragma clang fp contract(off)
  float dx = ax - bx;
  float dy = ay - by;
  float dz = az - bz;
  float t0 = dx * dx;
  float t1 = dy * dy;
  float t2 = dz * dz;
  return (t0 + t1) + t2;
}

// ---- wave64 reductions via DPP; result broadcast via readlane (uniform).
__device__ __forceinline__ float dpp_max_f32(float x) {
  int v;
  v = __builtin_amdgcn_update_dpp(__float_as_int(x), __float_as_int(x), 0xB1, 0xF, 0xF, false);
  x = fmaxf(x, __int_as_float(v));
  v = __builtin_amdgcn_update_dpp(__float_as_int(x), __float_as_int(x), 0x4E, 0xF, 0xF, false);
  x = fmaxf(x, __int_as_float(v));
  v = __builtin_amdgcn_update_dpp(__float_as_int(x), __float_as_int(x), 0x141, 0xF, 0xF, false);
  x = fmaxf(x, __int_as_float(v));
  v = __builtin_amdgcn_update_dpp(__float_as_int(x), __float_as_int(x), 0x140, 0xF, 0xF, false);
  x = fmaxf(x, __int_as_float(v));
  v = __builtin_amdgcn_update_dpp(__float_as_int(x), __float_as_int(x), 0x142, 0xA, 0xF, false);
  x = fmaxf(x, __int_as_float(v));
  v = __builtin_amdgcn_update_dpp(__float_as_int(x), __float_as_int(x), 0x143, 0xC, 0xF, false);
  x = fmaxf(x, __int_as_float(v));
  return __int_as_float(__builtin_amdgcn_readlane(__float_as_int(x), 63));
}

__device__ __forceinline__ int dpp_min_i32(int x) {
  int v;
  v = __builtin_amdgcn_update_dpp(x, x, 0xB1, 0xF, 0xF, false); x = min(x, v);
  v = __builtin_amdgcn_update_dpp(x, x, 0x4E, 0xF, 0xF, false); x = min(x, v);
  v = __builtin_amdgcn_update_dpp(x, x, 0x141, 0xF, 0xF, false); x = min(x, v);
  v = __builtin_amdgcn_update_dpp(x, x, 0x140, 0xF, 0xF, false); x = min(x, v);
  v = __builtin_amdgcn_update_dpp(x, x, 0x142, 0xA, 0xF, false); x = min(x, v);
  v = __builtin_amdgcn_update_dpp(x, x, 0x143, 0xC, 0xF, false); x = min(x, v);
  return __builtin_amdgcn_readlane(x, 63);
}

// ---------------- FPS: brute-force update (packed f32), 1 barrier/iter -------
// R16-validated, 1878 us. Thread tid owns 16 contiguous points as 8 float2
// pairs; d2e+fmin update uses v_pk_*_f32 (two IEEE f32 ops per instr,
// bit-identical rounding, same per-element op order -> dd bit-exact).
// Tie-break scan scalar strict-> ascending (= first index). DPP reduce +
// u64 key across waves; no in-loop global stores; batched writeback.
__global__ __launch_bounds__(512) void fps_kernel(const float* __restrict__ xyz,
                                                  float* __restrict__ out_xyz,
                                                  float* __restrict__ out_inds) {
  const int b = blockIdx.x;
  const int tid = threadIdx.x;
  const int lane = tid & 63, w = tid >> 6;

  __shared__ float2 sxy[NPTS];                  // original order
  __shared__ float  szl[NPTS];
  __shared__ unsigned short sslot[NPOINT];      // winner index per t
  __shared__ unsigned long long wred[2][8] __attribute__((aligned(16)));

  const float* xb = xyz + (size_t)b * NPTS * 3;

  // --- coalesced stage to LDS
  for (int k = 0; k < 16; k++) {
    int i = tid + k * 512;
    sxy[i] = make_float2(xb[i * 3 + 0], xb[i * 3 + 1]);
    szl[i] = xb[i * 3 + 2];
  }
  __syncthreads();

  const float2 q0xy = sxy[0];
  const float q0x = q0xy.x, q0y = q0xy.y, q0z = szl[0];

  // --- own 16 contiguous points as 8 packed pairs, init dd (packed, exact)
  const int base = tid * 16;
  v2f px2[8], py2[8], pz2[8], dd2[8];
  {
#pragma clang fp contract(off)
#pragma unroll
    for (int k = 0; k < 8; k++) {
      float2 a = sxy[base + 2 * k];
      float2 c = sxy[base + 2 * k + 1];
      px2[k] = (v2f){a.x, c.x};
      py2[k] = (v2f){a.y, c.y};
      pz2[k] = (v2f){szl[base + 2 * k], szl[base + 2 * k + 1]};
      v2f dx = px2[k] - q0x;
      v2f dy = py2[k] - q0y;
      v2f dz = pz2[k] - q0z;
      v2f t0 = dx * dx;
      v2f t1 = dy * dy;
      v2f t2 = dz * dz;
      dd2[k] = (t0 + t1) + t2;
    }
  }
  if (tid == 0) sslot[0] = 0;

  // --- initial scan (strict >, ascending = first index) + DPP reduce
  {
    float bv = -1.f; int bj = base;
#pragma unroll
    for (int k = 0; k < 8; k++) {
      float d0 = dd2[k].x, d1 = dd2[k].y;
      bool c0 = d0 > bv; bv = c0 ? d0 : bv; bj = c0 ? base + 2 * k : bj;
      bool c1 = d1 > bv; bv = c1 ? d1 : bv; bj = c1 ? base + 2 * k + 1 : bj;
    }
    float vm = dpp_max_f32(bv);
    int ci = (bv == vm) ? bj : 0x7FFFFFFF;
    int widx = dpp_min_i32(ci);
    if (lane == 0)
      wred[0][w] = ((unsigned long long)(~__float_as_uint(vm)) << 32) | (unsigned)widx;
  }
  __syncthreads();

  for (int t = 1; t < NPOINT; ++t) {
    // --- global winner = min of 8 wave keys (vectorized broadcast reads)
    const ulonglong2* wv = (const ulonglong2*)wred[(t - 1) & 1];
    ulonglong2 p0 = wv[0], p1 = wv[1], p2 = wv[2], p3 = wv[3];
    unsigned long long g0 = (p0.y < p0.x) ? p0.y : p0.x;
    unsigned long long g1 = (p1.y < p1.x) ? p1.y : p1.x;
    unsigned long long g2 = (p2.y < p2.x) ? p2.y : p2.x;
    unsigned long long g3 = (p3.y < p3.x) ? p3.y : p3.x;
    g0 = (g1 < g0) ? g1 : g0; g2 = (g3 < g2) ? g3 : g2;
    g0 = (g2 < g0) ? g2 : g0;
    const int nxt = (int)(g0 & 0xFFFFFFFFu);
    const float2 qxy = sxy[nxt];
    const float qx = qxy.x, qy = qxy.y, qz = szl[nxt];
    if (tid == 0) sslot[t] = (unsigned short)nxt;

    // --- packed straight-line update + scalar tie-aware scan (no branches)
    float bv = -1.f; int bj = base;
    {
#pragma clang fp contract(off)
#pragma unroll
      for (int k = 0; k < 8; k++) {
        v2f dx = px2[k] - qx;
        v2f dy = py2[k] - qy;
        v2f dz = pz2[k] - qz;
        v2f t0 = dx * dx;
        v2f t1 = dy * dy;
        v2f t2 = dz * dz;
        v2f d = (t0 + t1) + t2;
        v2f nd;
        nd.x = fminf(dd2[k].x, d.x);
        nd.y = fminf(dd2[k].y, d.y);
        dd2[k] = nd;
        bool c0 = nd.x > bv; bv = c0 ? nd.x : bv; bj = c0 ? base + 2 * k : bj;
        bool c1 = nd.y > bv; bv = c1 ? nd.y : bv; bj = c1 ? base + 2 * k + 1 : bj;
      }
    }
    float vm = dpp_max_f32(bv);
    int ci = (bv == vm) ? bj : 0x7FFFFFFF;
    int widx = dpp_min_i32(ci);
    if (lane == 0)
      wred[t & 1][w] = ((unsigned long long)(~__float_as_uint(vm)) << 32) | (unsigned)widx;
    __syncthreads();
  }

  // --- parallel writeback: inds + xyz from recorded winner indices
  for (int t = tid; t < NPOINT; t += 512) {
    int o = (int)sslot[t];
    float2 xy = sxy[o];
    out_inds[b * NPOINT + t] = (float)o;
    out_xyz[((size_t)b * NPOINT + t) * 3 + 0] = xy.x;
    out_xyz[((size_t)b * NPOINT + t) * 3 + 1] = xy.y;
    out_xyz[((size_t)b * NPOINT + t) * 3 + 2] = szl[o];
  }
}

// ---------------- prep: fold BN into per-channel consts ----------------------
// wsp floats: [0..255] A4[o]={sc0*W0x,sc0*W0y,sc0*W0z,sh0}; [256..319] sc1;
// [320..383] sh1; [384..511] sc2; [512..639] sh2; [640..703] sc0
__global__ __launch_bounds__(128) void prep_kernel(
    const float* __restrict__ W0, const float* __restrict__ g0,
    const float* __restrict__ b0, const float* __restrict__ m0,
    const float* __restrict__ v0, const float* __restrict__ g1,
    const float* __restrict__ b1, const float* __restrict__ m1,
    const float* __restrict__ v1, const float* __restrict__ g2,
    const float* __restrict__ b2, const float* __restrict__ m2,
    const float* __restrict__ v2, float* __restrict__ wsp) {
  const int tid = threadIdx.x;
  if (tid < 64) {
    float s0 = g0[tid] / sqrtf(v0[tid] + 1e-5f);
    wsp[4 * tid + 0] = s0 * W0[tid * K0 + 0];
    wsp[4 * tid + 1] = s0 * W0[tid * K0 + 1];
    wsp[4 * tid + 2] = s0 * W0[tid * K0 + 2];
    wsp[4 * tid + 3] = b0[tid] - m0[tid] * s0;
    wsp[640 + tid] = s0;
    float s1 = g1[tid] / sqrtf(v1[tid] + 1e-5f);
    wsp[256 + tid] = s1; wsp[320 + tid] = b1[tid] - m1[tid] * s1;
  }
  float s2 = g2[tid] / sqrtf(v2[tid] + 1e-5f);
  wsp[384 + tid] = s2; wsp[512 + tid] = b2[tid] - m2[tid] * s2;
}

// ---------------- zfeat: per-point L0 linear part ----------------------------
// szp[n][o] = sc0[o] * ( W0[o][0:3] . p_xyz + W0[o][3:67] . feat[:,n] )
__global__ __launch_bounds__(256) void zfeat_kernel(const float* __restrict__ xyz,
                                                    const float* __restrict__ feat,
                                                    const float* __restrict__ W0,
                                                    const float* __restrict__ wsp,
                                                    float* __restrict__ szp) {
  __shared__ float ftile[64][64];   // [c][u] - reads are wave-uniform
  __shared__ float sxyz[192];
  const int bt = blockIdx.x;        // b*128 + nt
  const int b = bt >> 7, nt = bt & 127;
  const int tid = threadIdx.x;
  const int lane = tid & 63, w = tid >> 6;

  const float* fb = feat + (size_t)b * 64 * NPTS + (size_t)nt * 64;
#pragma unroll
  for (int r = w; r < 64; r += 4)
    ftile[r][lane] = fb[(size_t)r * NPTS + lane];
  if (tid < 192)
    sxyz[tid] = xyz[((size_t)b * NPTS + (size_t)nt * 64) * 3 + tid];

  float w0x = W0[lane * K0 + 0], w0y = W0[lane * K0 + 1], w0z = W0[lane * K0 + 2];
  float wf[64];
#pragma unroll
  for (int i = 0; i < 64; i++) wf[i] = W0[lane * K0 + 3 + i];
  const float s0 = wsp[640 + lane];
  __syncthreads();

  float* ob = szp + ((size_t)b * NPTS + (size_t)nt * 64) * 64;
  for (int u = w; u < 64; u += 4) {
    float acc = w0x * sxyz[u * 3 + 0] + w0y * sxyz[u * 3 + 1] + w0z * sxyz[u * 3 + 2];
#pragma unroll
    for (int i = 0; i < 64; i++) acc = fmaf(wf[i], ftile[i][u], acc);
    ob[(size_t)u * 64 + lane] = acc * s0;
  }
}

// ---------------- ball query: one wave per query point -----------------------
__global__ __launch_bounds__(256) void ballq_kernel(const float* __restrict__ xyz,
                                                    const float* __restrict__ new_xyz,
                                                    int* __restrict__ ball) {
  const int lane = threadIdx.x & 63;
  const int q = blockIdx.x * 4 + (threadIdx.x >> 6);
  const int b = q >> 11;
  const float RR = (float)(0.4 * 0.4);
  const float cx = new_xyz[(size_t)q * 3 + 0];
  const float cy = new_xyz[(size_t)q * 3 + 1];
  const float cz = new_xyz[(size_t)q * 3 + 2];
  const float* xb = xyz + (size_t)b * NPTS * 3;
  int cnt = 0, firsti = -1;
  for (int base = 0; base < NPTS; base += 64) {
    int i = base + lane;
    float xx = xb[i * 3 + 0], yy = xb[i * 3 + 1], zz = xb[i * 3 + 2];
    float d2 = d2e(xx, yy, zz, cx, cy, cz);
    bool m = d2 < RR;
    unsigned long long mask = __ballot(m);
    if (mask) {
      if (firsti < 0) firsti = base + (__ffsll((unsigned long long)mask) - 1);
      int pos = cnt + (int)__popcll(mask & ((1ull << lane) - 1ull));
      if (m && pos < NSAMPLE) ball[(size_t)q * NSAMPLE + pos] = i;
      cnt += (int)__popcll(mask);
      if (cnt >= NSAMPLE) break;
    }
  }
  for (int s = cnt + lane; s < NSAMPLE; s += 64)
    ball[(size_t)q * NSAMPLE + s] = firsti;
}

// ---------------- MLP L1/L2 + max-pool: lane = channel (R9 body, 672us tail) -
#define QPW 4
__global__ __launch_bounds__(256, 2) void mlp_kernel(
    const float* __restrict__ szp, const int* __restrict__ ball,
    const float* __restrict__ new_xyz, const float* __restrict__ W1,
    const float* __restrict__ W2, const float* __restrict__ wsp,
    float* __restrict__ out_feat) {
  __shared__ float ylds[4][64];
  __shared__ int   blds[4][64];
  const int tid = threadIdx.x;
  const int lane = tid & 63, wid = tid >> 6;

  float4 w1v[16], w2av[16], w2bv[16];
  const float4* W1r = (const float4*)(W1 + lane * 64);
  const float4* W2ar = (const float4*)(W2 + lane * 64);
  const float4* W2br = (const float4*)(W2 + (lane + 64) * 64);
#pragma unroll
  for (int i = 0; i < 16; i++) { w1v[i] = W1r[i]; w2av[i] = W2ar[i]; w2bv[i] = W2br[i]; }
  const float4 A = ((const float4*)wsp)[lane];
  const float sc1l = wsp[256 + lane], sh1l = wsp[320 + lane];
  const float sc2al = wsp[384 + lane], sh2al = wsp[512 + lane];
  const float sc2bl = wsp[448 + lane], sh2bl = wsp[576 + lane];

  for (int qi = 0; qi < QPW; qi++) {
    const int q = blockIdx.x * (4 * QPW) + qi * 4 + wid;
    const int b = q >> 11, p = q & 2047;

    const float cx = new_xyz[(size_t)q * 3 + 0];
    const float cy = new_xyz[(size_t)q * 3 + 1];
    const float cz = new_xyz[(size_t)q * 3 + 2];
    const float hc = A.w - (A.x * cx + A.y * cy + A.z * cz);

    blds[wid][lane] = ball[(size_t)q * NSAMPLE + lane];
    const float* szb = szp + (size_t)b * NPTS * 64;
    __builtin_amdgcn_s_waitcnt(0);   // vm+lgkm: blds visible to own wave

    float vA = 0.f, vB = 0.f;
    int idx0 = blds[wid][0];
    float fcur = szb[(size_t)idx0 * 64 + lane];
    const float4* yv = (const float4*)ylds[wid];

    for (int s = 0; s < NSAMPLE; s++) {
      int sn = (s < NSAMPLE - 1) ? s + 1 : s;
      int idxn = blds[wid][sn];
      float fnext = szb[(size_t)idxn * 64 + lane];

      float y0 = fmaxf(fcur + hc, 0.f);
      ylds[wid][lane] = y0;
      float a0 = 0.f, a1 = 0.f, a2 = 0.f, a3 = 0.f;
#pragma unroll
      for (int i = 0; i < 16; i++) {
        float4 y = yv[i];
        a0 = fmaf(w1v[i].x, y.x, a0);
        a1 = fmaf(w1v[i].y, y.y, a1);
        a2 = fmaf(w1v[i].z, y.z, a2);
        a3 = fmaf(w1v[i].w, y.w, a3);
      }
      float y1 = fmaxf(fmaf((a0 + a1) + (a2 + a3), sc1l, sh1l), 0.f);
      ylds[wid][lane] = y1;
      float c0 = 0.f, c1 = 0.f, c2 = 0.f, c3 = 0.f;
      float e0 = 0.f, e1 = 0.f, e2 = 0.f, e3 = 0.f;
#pragma unroll
      for (int i = 0; i < 16; i++) {
        float4 y = yv[i];
        c0 = fmaf(w2av[i].x, y.x, c0);
        c1 = fmaf(w2av[i].y, y.y, c1);
        c2 = fmaf(w2av[i].z, y.z, c2);
        c3 = fmaf(w2av[i].w, y.w, c3);
        e0 = fmaf(w2bv[i].x, y.x, e0);
        e1 = fmaf(w2bv[i].y, y.y, e1);
        e2 = fmaf(w2bv[i].z, y.z, e2);
        e3 = fmaf(w2bv[i].w, y.w, e3);
      }
      float y2a = fmaxf(fmaf((c0 + c1) + (c2 + c3), sc2al, sh2al), 0.f);
      float y2b = fmaxf(fmaf((e0 + e1) + (e2 + e3), sc2bl, sh2bl), 0.f);
      vA = fmaxf(vA, y2a);
      vB = fmaxf(vB, y2b);
      fcur = fnext;
    }
    out_feat[((size_t)b * C2 + lane) * NPOINT + p] = vA;
    out_feat[((size_t)b * C2 + lane + 64) * NPOINT + p] = vB;
  }
}

extern "C" void kernel_launch(void* const* d_in, const int* in_sizes, int n_in,
                              void* d_out, int out_size, void* d_ws, size_t ws_size,
                              hipStream_t stream) {
  const float* xyz  = (const float*)d_in[0];
  const float* feat = (const float*)d_in[1];
  const float* W0 = (const float*)d_in[2];
  const float* g0 = (const float*)d_in[3];
  const float* b0 = (const float*)d_in[4];
  const float* m0 = (const float*)d_in[5];
  const float* v0 = (const float*)d_in[6];
  const float* W1 = (const float*)d_in[7];
  const float* g1 = (const float*)d_in[8];
  const float* b1 = (const float*)d_in[9];
  const float* m1 = (const float*)d_in[10];
  const float* v1 = (const float*)d_in[11];
  const float* W2 = (const float*)d_in[12];
  const float* g2 = (const float*)d_in[13];
  const float* b2 = (const float*)d_in[14];
  const float* m2 = (const float*)d_in[15];
  const float* v2 = (const float*)d_in[16];

  float* out = (float*)d_out;
  float* out_xyz  = out;                         // (8,2048,3)   = 49152
  float* out_feat = out + 49152;                 // (8,128,2048) = 2097152
  float* out_inds = out + 49152 + 2097152;       // (8,2048)     = 16384

  int*   ball = (int*)d_ws;                                      // 4 MiB
  float* szp  = (float*)((char*)d_ws + 4194304);                 // 16.8 MiB
  float* wsp  = (float*)((char*)d_ws + 20971520);                // ~3 KiB

  hipLaunchKernelGGL(prep_kernel, dim3(1), dim3(128), 0, stream,
                     W0, g0, b0, m0, v0, g1, b1, m1, v1, g2, b2, m2, v2, wsp);
  hipLaunchKernelGGL(zfeat_kernel, dim3(BATCH * (NPTS / 64)), dim3(256), 0, stream,
                     xyz, feat, W0, wsp, szp);
  hipLaunchKernelGGL(fps_kernel, dim3(BATCH), dim3(512), 0, stream,
                     xyz, out_xyz, out_inds);
  hipLaunchKernelGGL(ballq_kernel, dim3((BATCH * NPOINT) / 4), dim3(256), 0, stream,
                     xyz, out_xyz, ball);
  hipLaunchKernelGGL(mlp_kernel, dim3((BATCH * NPOINT) / (4 * QPW)), dim3(256), 0, stream,
                     szp, ball, out_xyz, W1, W2, wsp, out_feat);
}